// Round 2
// baseline (7679.426 us; speedup 1.0000x reference)
//
#include <hip/hip_runtime.h>
#include <stdint.h>

#define BB 4
#define NN 4096
#define DD 64
#define BN (BB*NN)
#define STABF 1e-8f
#define NITER 100
#define TOLF 1e-5f
// exp(-cost/eps) = exp2(cost * -1000*log2(e))
#define NEG_SCALE (-1442.695040888963f)

__device__ __forceinline__ float bf16lo(uint32_t w){ return __uint_as_float(w << 16); }
__device__ __forceinline__ float bf16hi(uint32_t w){ return __uint_as_float(w & 0xffff0000u); }
__device__ __forceinline__ uint32_t pack2bf(float f0, float f1){
  uint32_t u0 = __float_as_uint(f0); u0 += 0x7fffu + ((u0 >> 16) & 1u);
  uint32_t u1 = __float_as_uint(f1); u1 += 0x7fffu + ((u1 >> 16) & 1u);
  return (u0 >> 16) | (u1 & 0xffff0000u);
}
__device__ __forceinline__ unsigned short f2bf(float f){
  uint32_t u = __float_as_uint(f); u += 0x7fffu + ((u >> 16) & 1u);
  return (unsigned short)(u >> 16);
}

// ---------------- init: au0=au1=0, av1=N (v0=1/N), d[0]=inf-ish, d[1..]=0, partial=0
__global__ __launch_bounds__(256) void k_init(float* __restrict__ au0,
                                              float* __restrict__ au1,
                                              float* __restrict__ av1,
                                              float* __restrict__ dly,
                                              float* __restrict__ partial) {
  int idx = blockIdx.x * 256 + threadIdx.x;   // grid 64 -> 16384 threads
  if (idx < BN) { au0[idx] = 0.f; au1[idx] = 0.f; av1[idx] = (float)NN; }
  if (idx < 256) partial[idx] = 0.f;
  if (idx < 128) dly[idx] = (idx == 0) ? 1e30f : 0.f;
}

// ---------------- softmax over last dim (64) for both x and y; also sum(p^2)
__global__ __launch_bounds__(256) void k_softmax(
    const float* __restrict__ x, const float* __restrict__ y,
    float* __restrict__ xf, float* __restrict__ yf,
    float* __restrict__ x2, float* __restrict__ y2) {
  int wave = (blockIdx.x * 256 + threadIdx.x) >> 6;   // grid 8192 -> 32768 waves
  int lane = threadIdx.x & 63;
  const float* src; float* dst; float* d2; int row;
  if (wave < BN) { src = x; dst = xf; d2 = x2; row = wave; }
  else           { src = y; dst = yf; d2 = y2; row = wave - BN; }
  float v = src[(size_t)row * DD + lane];
  float m = v;
  #pragma unroll
  for (int off = 32; off; off >>= 1) m = fmaxf(m, __shfl_xor(m, off));
  float e = __expf(v - m);
  float s = e;
  #pragma unroll
  for (int off = 32; off; off >>= 1) s += __shfl_xor(s, off);
  float p = e / s;
  dst[(size_t)row * DD + lane] = p;
  float q = p * p;
  #pragma unroll
  for (int off = 32; off; off >>= 1) q += __shfl_xor(q, off);
  if (lane == 0) d2[row] = q;
}

__device__ __forceinline__ void fma_row(float av0, float av1, const float4 bv,
                                        float cr0[4], float cr1[4]) {
  cr0[0] = fmaf(av0, bv.x, cr0[0]); cr0[1] = fmaf(av0, bv.y, cr0[1]);
  cr0[2] = fmaf(av0, bv.z, cr0[2]); cr0[3] = fmaf(av0, bv.w, cr0[3]);
  cr1[0] = fmaf(av1, bv.x, cr1[0]); cr1[1] = fmaf(av1, bv.y, cr1[1]);
  cr1[2] = fmaf(av1, bv.z, cr1[2]); cr1[3] = fmaf(av1, bv.w, cr1[3]);
}

// ---------------- build K (bf16) and optionally KT (bf16, transposed via LDS)
__global__ __launch_bounds__(256) void k_build(
    const float* __restrict__ xf, const float* __restrict__ yf,
    const float* __restrict__ x2, const float* __restrict__ y2,
    unsigned short* __restrict__ K, unsigned short* __restrict__ KT,
    int useKT) {
  __shared__ float sxf[32][68];
  __shared__ float syt[64][68];   // transposed: syt[d][j]
  __shared__ unsigned short kts[64][40];  // [j][i], 80B row stride: 16B-aligned
  int bid = blockIdx.x, t = threadIdx.x;
  int jt = bid & 63, it = (bid >> 6) & 127, b = bid >> 13;
  int i0 = it * 32, j0 = jt * 64;
  {
    int r = t >> 3, c = (t & 7) * 8;
    const float* s0 = xf + ((size_t)(b*NN + i0 + r)) * DD + c;
    *(float4*)&sxf[r][c]     = *(const float4*)s0;
    *(float4*)&sxf[r][c + 4] = *(const float4*)(s0 + 4);
  }
  {
    int r = t >> 2, c0 = (t & 3) * 16;
    const float* s0 = yf + ((size_t)(b*NN + j0 + r)) * DD + c0;
    #pragma unroll
    for (int q = 0; q < 4; ++q) {
      float4 pv = *(const float4*)(s0 + q*4);
      syt[c0 + q*4 + 0][r] = pv.x;
      syt[c0 + q*4 + 1][r] = pv.y;
      syt[c0 + q*4 + 2][r] = pv.z;
      syt[c0 + q*4 + 3][r] = pv.w;
    }
  }
  __syncthreads();
  int tx = t & 15, ty = t >> 4;
  int ii = ty * 2, jj = tx * 4;
  float cr[2][4] = {{0,0,0,0},{0,0,0,0}};
  #pragma unroll
  for (int d = 0; d < DD; d += 4) {
    float4 a0 = *(const float4*)&sxf[ii][d];
    float4 a1 = *(const float4*)&sxf[ii + 1][d];
    float4 b0 = *(const float4*)&syt[d][jj];
    float4 b1 = *(const float4*)&syt[d + 1][jj];
    float4 b2 = *(const float4*)&syt[d + 2][jj];
    float4 b3 = *(const float4*)&syt[d + 3][jj];
    fma_row(a0.x, a1.x, b0, cr[0], cr[1]);
    fma_row(a0.y, a1.y, b1, cr[0], cr[1]);
    fma_row(a0.z, a1.z, b2, cr[0], cr[1]);
    fma_row(a0.w, a1.w, b3, cr[0], cr[1]);
  }
  float x2v[2], y2v[4];
  x2v[0] = x2[b*NN + i0 + ii]; x2v[1] = x2[b*NN + i0 + ii + 1];
  #pragma unroll
  for (int c = 0; c < 4; ++c) y2v[c] = y2[b*NN + j0 + jj + c];
  #pragma unroll
  for (int i2 = 0; i2 < 2; ++i2) {
    float k4[4];
    #pragma unroll
    for (int c = 0; c < 4; ++c) {
      float cost = fmaxf(x2v[i2] + y2v[c] - 2.f * cr[i2][c], 0.f);
      k4[c] = exp2f(cost * NEG_SCALE);
    }
    uint2 kw;
    kw.x = pack2bf(k4[0], k4[1]);
    kw.y = pack2bf(k4[2], k4[3]);
    *(uint2*)(K + ((size_t)(b*NN + i0 + ii + i2)) * NN + j0 + jj) = kw;
    if (useKT) {
      #pragma unroll
      for (int c = 0; c < 4; ++c) kts[jj + c][ii + i2] = f2bf(k4[c]);
    }
  }
  if (useKT) {
    __syncthreads();
    int r = t >> 2, cc = (t & 3) * 8;   // 64 rows (j), 4x8 i-chunks
    uint4 v = *(const uint4*)&kts[r][cc];
    *(uint4*)(KT + ((size_t)(b*NN + j0 + r)) * NN + i0 + cc) = v;
  }
}

// ---------------- shared slab pass (coldot shape):
// vout[c] += sum_r M[r][c] * rcp(vin[r]+stab), over block's 64 rows x 2048 cols.
// Blocks 0-15 also: (col pass, dwrite!=0) delta(vin vs zbuf) -> atomicMax dwrite,
// then zero zbuf;  (row pass, dwrite==0) just zero zbuf.
// Frozen (d[t]<TOL): col pass returns; row pass syncs slots (vout<-oldbuf, zbuf<-vin).
__global__ __launch_bounds__(256) void k_pass(
    const unsigned short* __restrict__ M, const float* __restrict__ vin,
    float* __restrict__ vout, float* __restrict__ zbuf,
    const float* __restrict__ oldbuf, const float* __restrict__ dread,
    float* dwrite) {
  int bid = blockIdx.x, t = threadIdx.x;
  float dv = *dread;
  if (dv < TOLF) {
    if (dwrite == nullptr && bid < 16) {
      int i0 = bid * 1024 + t * 4;
      #pragma unroll
      for (int k = 0; k < 4; ++k) { vout[i0+k] = oldbuf[i0+k]; zbuf[i0+k] = vin[i0+k]; }
    }
    return;
  }
  if (bid < 16) {
    int i0 = bid * 1024 + t * 4;
    if (dwrite) {
      float mx = 0.f;
      #pragma unroll
      for (int k = 0; k < 4; ++k) {
        float nw = vin[i0+k], od = zbuf[i0+k];
        mx = fmaxf(mx, fabsf(nw - od) * __builtin_amdgcn_rcpf(fabsf(nw) + 1e-30f));
      }
      #pragma unroll
      for (int off = 32; off; off >>= 1) mx = fmaxf(mx, __shfl_xor(mx, off));
      if ((t & 63) == 0) atomicMax((unsigned int*)dwrite, __float_as_uint(mx));
    }
    #pragma unroll
    for (int k = 0; k < 4; ++k) zbuf[i0+k] = 0.f;
  }
  __shared__ float su[64];
  int b = bid >> 7, slab = (bid >> 6) & 1, chunk = bid & 63;   // grid 512
  int r0 = chunk * 64, c0 = slab * 2048 + t * 8;
  if (t < 64) su[t] = __builtin_amdgcn_rcpf(vin[b*NN + r0 + t] + STABF);
  __syncthreads();
  const unsigned short* Mp = M + ((size_t)(b*NN + r0)) * NN + c0;
  float s0=0,s1=0,s2=0,s3=0,s4=0,s5=0,s6=0,s7=0;
  #pragma unroll 4
  for (int r = 0; r < 64; ++r) {
    uint4 kw = *(const uint4*)(Mp + (size_t)r * NN);
    float ur = su[r];
    s0 = fmaf(bf16lo(kw.x), ur, s0);
    s1 = fmaf(bf16hi(kw.x), ur, s1);
    s2 = fmaf(bf16lo(kw.y), ur, s2);
    s3 = fmaf(bf16hi(kw.y), ur, s3);
    s4 = fmaf(bf16lo(kw.z), ur, s4);
    s5 = fmaf(bf16hi(kw.z), ur, s5);
    s6 = fmaf(bf16lo(kw.w), ur, s6);
    s7 = fmaf(bf16hi(kw.w), ur, s7);
  }
  float* op = vout + b*NN + c0;
  atomicAdd(op + 0, s0); atomicAdd(op + 1, s1);
  atomicAdd(op + 2, s2); atomicAdd(op + 3, s3);
  atomicAdd(op + 4, s4); atomicAdd(op + 5, s5);
  atomicAdd(op + 6, s6); atomicAdd(op + 7, s7);
}

// ---------------- fallback row pass (no KT): LDS-cached v, wave-per-row.
// vout[row] = sum_j K[row][j]*rcp(vin[j]+stab); blocks 0-15 zero zbuf / freeze-copy.
__global__ __launch_bounds__(256) void k_rowdot_b(
    const unsigned short* __restrict__ K, const float* __restrict__ vin,
    float* __restrict__ vout, float* __restrict__ zbuf,
    const float* __restrict__ oldbuf, const float* __restrict__ dread) {
  int bid = blockIdx.x, t = threadIdx.x;     // grid 1024: 16 rows/block
  float dv = *dread;
  if (dv < TOLF) {
    if (bid < 16) {
      int i0 = bid * 1024 + t * 4;
      #pragma unroll
      for (int k = 0; k < 4; ++k) { vout[i0+k] = oldbuf[i0+k]; zbuf[i0+k] = vin[i0+k]; }
    }
    return;
  }
  if (bid < 16) {
    int i0 = bid * 1024 + t * 4;
    #pragma unroll
    for (int k = 0; k < 4; ++k) zbuf[i0+k] = 0.f;
  }
  __shared__ float vs[NN];
  int b = bid >> 8, g = bid & 255;
  const float* vp = vin + b * NN;
  #pragma unroll
  for (int k = 0; k < 4; ++k) {
    float4 a = *(const float4*)(vp + t * 16 + k * 4);
    vs[t*16 + k*4 + 0] = __builtin_amdgcn_rcpf(a.x + STABF);
    vs[t*16 + k*4 + 1] = __builtin_amdgcn_rcpf(a.y + STABF);
    vs[t*16 + k*4 + 2] = __builtin_amdgcn_rcpf(a.z + STABF);
    vs[t*16 + k*4 + 3] = __builtin_amdgcn_rcpf(a.w + STABF);
  }
  __syncthreads();
  int wave = t >> 6, lane = t & 63;
  int r0 = g * 16 + wave * 4;
  for (int rr = 0; rr < 4; ++rr) {
    int row = r0 + rr;
    const unsigned short* Kp = K + ((size_t)(b*NN + row)) * NN;
    float sum = 0.f;
    #pragma unroll
    for (int c = 0; c < 8; ++c) {
      int j = c * 512 + lane * 8;
      uint4 kw = *(const uint4*)(Kp + j);
      float4 v0 = *(const float4*)&vs[j];
      float4 v1 = *(const float4*)&vs[j + 4];
      sum = fmaf(bf16lo(kw.x), v0.x, sum);
      sum = fmaf(bf16hi(kw.x), v0.y, sum);
      sum = fmaf(bf16lo(kw.y), v0.z, sum);
      sum = fmaf(bf16hi(kw.y), v0.w, sum);
      sum = fmaf(bf16lo(kw.z), v1.x, sum);
      sum = fmaf(bf16hi(kw.z), v1.y, sum);
      sum = fmaf(bf16lo(kw.w), v1.z, sum);
      sum = fmaf(bf16hi(kw.w), v1.w, sum);
    }
    #pragma unroll
    for (int off = 32; off; off >>= 1) sum += __shfl_xor(sum, off);
    if (lane == 0) vout[b*NN + row] = sum;
  }
}

// ---------------- dist partials: sum u_i K_ij v_j cost_ij (cost recomputed)
__global__ __launch_bounds__(256) void k_final(
    const float* __restrict__ xf, const float* __restrict__ yf,
    const float* __restrict__ x2, const float* __restrict__ y2,
    const unsigned short* __restrict__ K, const float* __restrict__ auf,
    const float* __restrict__ avf, float* __restrict__ partial) {
  __shared__ float sxf[32][68];
  __shared__ float syt[64][68];
  __shared__ float red[256];
  int bid = blockIdx.x, t = threadIdx.x;
  int jt = bid & 63, it = (bid >> 6) & 127, b = bid >> 13;
  int i0 = it * 32, j0 = jt * 64;
  {
    int r = t >> 3, c = (t & 7) * 8;
    const float* s0 = xf + ((size_t)(b*NN + i0 + r)) * DD + c;
    *(float4*)&sxf[r][c]     = *(const float4*)s0;
    *(float4*)&sxf[r][c + 4] = *(const float4*)(s0 + 4);
  }
  {
    int r = t >> 2, c0 = (t & 3) * 16;
    const float* s0 = yf + ((size_t)(b*NN + j0 + r)) * DD + c0;
    #pragma unroll
    for (int q = 0; q < 4; ++q) {
      float4 pv = *(const float4*)(s0 + q*4);
      syt[c0 + q*4 + 0][r] = pv.x;
      syt[c0 + q*4 + 1][r] = pv.y;
      syt[c0 + q*4 + 2][r] = pv.z;
      syt[c0 + q*4 + 3][r] = pv.w;
    }
  }
  __syncthreads();
  int tx = t & 15, ty = t >> 4;
  int ii = ty * 2, jj = tx * 4;
  float cr[2][4] = {{0,0,0,0},{0,0,0,0}};
  #pragma unroll
  for (int d = 0; d < DD; d += 4) {
    float4 a0 = *(const float4*)&sxf[ii][d];
    float4 a1 = *(const float4*)&sxf[ii + 1][d];
    float4 b0 = *(const float4*)&syt[d][jj];
    float4 b1 = *(const float4*)&syt[d + 1][jj];
    float4 b2 = *(const float4*)&syt[d + 2][jj];
    float4 b3 = *(const float4*)&syt[d + 3][jj];
    fma_row(a0.x, a1.x, b0, cr[0], cr[1]);
    fma_row(a0.y, a1.y, b1, cr[0], cr[1]);
    fma_row(a0.z, a1.z, b2, cr[0], cr[1]);
    fma_row(a0.w, a1.w, b3, cr[0], cr[1]);
  }
  float x2v[2], y2v[4], uv[2], vv[4];
  x2v[0] = x2[b*NN + i0 + ii]; x2v[1] = x2[b*NN + i0 + ii + 1];
  uv[0] = __builtin_amdgcn_rcpf(auf[b*NN + i0 + ii] + STABF);
  uv[1] = __builtin_amdgcn_rcpf(auf[b*NN + i0 + ii + 1] + STABF);
  #pragma unroll
  for (int c = 0; c < 4; ++c) {
    y2v[c] = y2[b*NN + j0 + jj + c];
    vv[c]  = __builtin_amdgcn_rcpf(avf[b*NN + j0 + jj + c] + STABF);
  }
  float s = 0.f;
  #pragma unroll
  for (int i2 = 0; i2 < 2; ++i2) {
    uint2 kw = *(const uint2*)(K + ((size_t)(b*NN + i0 + ii + i2)) * NN + j0 + jj);
    float kk[4] = {bf16lo(kw.x), bf16hi(kw.x), bf16lo(kw.y), bf16hi(kw.y)};
    #pragma unroll
    for (int c = 0; c < 4; ++c) {
      float cost = fmaxf(x2v[i2] + y2v[c] - 2.f * cr[i2][c], 0.f);
      s = fmaf(uv[i2] * kk[c] * vv[c], cost, s);
    }
  }
  red[t] = s;
  __syncthreads();
  #pragma unroll
  for (int off = 128; off; off >>= 1) {
    if (t < off) red[t] += red[t + off];
    __syncthreads();
  }
  if (t == 0) atomicAdd(partial + (bid & 255), red[0]);
}

__global__ __launch_bounds__(256) void k_finalize(const float* __restrict__ partial,
                                                 float* __restrict__ out) {
  __shared__ float red[256];
  int t = threadIdx.x;
  red[t] = partial[t];
  __syncthreads();
  #pragma unroll
  for (int off = 128; off; off >>= 1) {
    if (t < off) red[t] += red[t + off];
    __syncthreads();
  }
  if (t == 0) out[0] = red[0];
}

extern "C" void kernel_launch(void* const* d_in, const int* in_sizes, int n_in,
                              void* d_out, int out_size, void* d_ws, size_t ws_size,
                              hipStream_t stream) {
  const float* x = (const float*)d_in[0];
  const float* y = (const float*)d_in[1];
  float* out = (float*)d_out;

  char* w = (char*)d_ws;
  unsigned short* K = (unsigned short*)w;                   // 134,217,728 B
  float* xf = (float*)(w + 134217728ull);                   // 4 MB
  float* yf = xf + (size_t)BN * DD;                         // 4 MB
  float* x2 = yf + (size_t)BN * DD;                         // 64 KB
  float* y2 = x2 + BN;                                      // 64 KB
  float* au0 = y2 + BN;                                     // 64 KB
  float* au1 = au0 + BN;
  float* av0 = au1 + BN;
  float* av1 = av0 + BN;
  float* dly = av1 + BN;                                    // 128 floats
  float* partial = dly + 128;                               // 256 floats
  unsigned short* KT = (unsigned short*)(w + 143001600ull); // 134,217,728 B
  bool useA = ws_size >= 277219328ull;
  float* au[2] = {au0, au1};
  float* av[2] = {av0, av1};
  (void)in_sizes; (void)n_in; (void)out_size;

  k_init<<<64, 256, 0, stream>>>(au0, au1, av1, dly, partial);
  k_softmax<<<8192, 256, 0, stream>>>(x, y, xf, yf, x2, y2);
  k_build<<<32768, 256, 0, stream>>>(xf, yf, x2, y2, K, KT, useA ? 1 : 0);

  for (int tt = 0; tt < NITER; ++tt) {
    int p = tt & 1, q = 1 - p;
    if (useA) {
      // row pass on KT: au[p] += KT[j][:] * rcp(av[q][j]); zero av[p]
      k_pass<<<512, 256, 0, stream>>>(KT, av[q], au[p], av[p], au[q], dly + tt, nullptr);
    } else {
      k_rowdot_b<<<1024, 256, 0, stream>>>(K, av[q], au[p], av[p], au[q], dly + tt);
    }
    // col pass on K: av[p] += K[i][:] * rcp(au[p][i]); delta(au[p],au[q]) -> d[t+1]; zero au[q]
    k_pass<<<512, 256, 0, stream>>>(K, au[p], av[p], au[q], au[q], dly + tt, dly + tt + 1);
  }
  // after t=99 (p=1), slot 1 holds latest au/av (frozen path keeps slots synced)
  k_final<<<32768, 256, 0, stream>>>(xf, yf, x2, y2, K, au1, av1, partial);
  k_finalize<<<1, 256, 0, stream>>>(partial, out);
}